// Round 13
// baseline (139.784 us; speedup 1.0000x reference)
//
#include <hip/hip_runtime.h>
#include <stdint.h>
#include <math.h>

#define B_DIM 4096
#define H_DIM 1024
#define NI_DIM 4096
#define NQ_DIM 2048
#define K_DIM 5120   // H + NI
#define NKT 160      // K_DIM / 32

typedef __attribute__((ext_vector_type(8))) short short8;
typedef __attribute__((ext_vector_type(4))) float f32x4;

__device__ __forceinline__ unsigned short f2bf(float f) {
  unsigned u = __float_as_uint(f);
  u += 0x7FFFu + ((u >> 16) & 1u);  // round-to-nearest-even
  return (unsigned short)(u >> 16);
}
__device__ __forceinline__ float bf2f(unsigned short s) {
  return __uint_as_float(((unsigned)s) << 16);
}
__device__ __forceinline__ unsigned pkbf(float a, float b) {
  unsigned r;
  asm("v_cvt_pk_bf16_f32 %0, %1, %2" : "=v"(r) : "v"(a), "v"(b));
  return r;
}

__device__ __forceinline__ void gload_lds16(const void* g, void* l) {
  __builtin_amdgcn_global_load_lds(
      (__attribute__((address_space(1))) void*)(uintptr_t)g,
      (__attribute__((address_space(3))) void*)l, 16, 0, 0);
}

// fp32 -> bf16 cast into staged-tile layout. Identical to the proven
// cast_v4 except the global stores are NONTEMPORAL: R8 counters showed
// cold FETCH_SIZE == WRITE_SIZE (write-allocate RFO on every output
// line) while input reads were L3-served -- the cast was RFO-bound,
// not occupancy/pattern-bound. Streaming stores skip the allocate.
__global__ __launch_bounds__(256) void cast_v4(
    const float* __restrict__ X0, const float* __restrict__ X1,
    const float* __restrict__ W0, const float* __restrict__ W1,
    short* __restrict__ Xc, short* __restrict__ Wc) {
  __shared__ __align__(16) short lds[16384];  // 2048 chunks x 8 shorts
  int bt = blockIdx.x;
  const float *s0, *s1;
  short* dst;
  if (bt < (B_DIM / 128) * (NKT / 4)) { s0 = X0; s1 = X1; dst = Xc; }
  else { bt -= (B_DIM / 128) * (NKT / 4); s0 = W0; s1 = W1; dst = Wc; }
  const int rowTile = bt / (NKT / 4);
  const int K0 = (bt % (NKT / 4)) * 4;       // first kt of this block
  const float* src;
  int cols, colBase;
  if (K0 < 32) { src = s0; cols = 1024; colBase = K0 * 32; }
  else         { src = s1; cols = 4096; colBase = (K0 - 32) * 32; }
  const int tid = threadIdx.x;
  const int kc = tid & 31;      // float4 col chunk within 128 cols
  const int r0 = tid >> 5;      // starting row (8 rows per pass)
#pragma unroll
  for (int i = 0; i < 16; ++i) {
    int r = r0 + i * 8;
    float4 v = *(const float4*)(src +
        (long long)(rowTile * 128 + r) * cols + colBase + kc * 4);
    uint2 o;
    o.x = pkbf(v.x, v.y);
    o.y = pkbf(v.z, v.w);
    int l = (kc >> 1) * 128 + r;          // logical chunk (s16*128 + r)
    int p = l ^ ((l >> 7) & 7);           // physical (bank-spread)
    *(uint2*)(&lds[p * 8 + (kc & 1) * 4]) = o;
  }
  __syncthreads();
  short* dbase = dst + ((long long)rowTile * NKT + K0) * 4096;
#pragma unroll
  for (int i = 0; i < 8; ++i) {
    int c = tid + i * 256;
    int p = c ^ ((c >> 7) & 7);
    __builtin_nontemporal_store(*(const short8*)(&lds[p * 8]),
                                (short8*)(dbase + c * 8));
  }
}

// LDS byte-swizzle for the epilogue transpose buffer [col][row] bf16.
__device__ __forceinline__ int ep_swz(int col, int rw) {
  int byte = col * 256 + rw * 2;
  byte ^= ((col ^ (col >> 3)) & 7) << 4;   // spread banks, keeps 8B align
  return byte;
}

// Split-K GEMM (proven: 46.5us, 923 TF, MfmaUtil 39%, conflicts
// epilogue-only). 128x128 tile, BK=32, 4 waves (2x2), dbuf LDS via
// global_load_lds w=16 on staged-tile Xc/Wc; bf16 partials via
// LDS-transposed coalesced epilogue. DO NOT TOUCH (R4/R10/R11/R12 all
// lost to this structure).
__global__ __launch_bounds__(256, 4) void gemm_splitk(
    const short* __restrict__ Xc, const short* __restrict__ Wc,
    short* __restrict__ P, int ntk) {
  __shared__ __align__(16) short SH[16384];  // A dbuf 16KB | B dbuf 16KB
  const int tid = threadIdx.x;
  const int lane = tid & 63;
  const int wid = tid >> 6;
  const int wm = wid >> 1, wn = wid & 1;
  const int fr = lane & 15, fq = lane >> 4;

  const int nwg = gridDim.x;
  const int orig = blockIdx.x;
  const int cpx = nwg >> 3;
  const int swz = (orig & 7) * cpx + (orig >> 3);
  const int bz = swz >> 8;
  const int bm = (swz >> 3) & 31;
  const int bn = swz & 7;
  const int kt0 = bz * ntk;

  const int c0 = tid, c1 = tid + 256;
  const short* gA = Xc + (((long long)bm * NKT + kt0) << 12);  // *4096 shorts
  const short* gB = Wc + (((long long)bn * NKT + kt0) << 12);

  f32x4 acc[4][4] = {};

  gload_lds16(gA + c0 * 8, &SH[c0 * 8]);
  gload_lds16(gA + c1 * 8, &SH[c1 * 8]);
  gload_lds16(gB + c0 * 8, &SH[8192 + c0 * 8]);
  gload_lds16(gB + c1 * 8, &SH[8192 + c1 * 8]);
  __syncthreads();

  int cur = 0;
  for (int t = 0; t < ntk; ++t) {
    if (t + 1 < ntk) {
      const short* nA = gA + (long long)(t + 1) * 4096;
      const short* nB = gB + (long long)(t + 1) * 4096;
      short* lA = &SH[(cur ^ 1) * 4096];
      short* lB = &SH[8192 + (cur ^ 1) * 4096];
      gload_lds16(nA + c0 * 8, lA + c0 * 8);
      gload_lds16(nA + c1 * 8, lA + c1 * 8);
      gload_lds16(nB + c0 * 8, lB + c0 * 8);
      gload_lds16(nB + c1 * 8, lB + c1 * 8);
    }
    const short* a_base = &SH[cur * 4096];
    const short* b_base = &SH[8192 + cur * 4096];
    short8 av[4], bv[4];
#pragma unroll
    for (int i = 0; i < 4; i++) {
      // [slot=fq][row = w*64 + i*16 + fr][8] -> conflict-free granules
      av[i] = *(const short8*)(a_base + (fq * 128 + wm * 64 + i * 16 + fr) * 8);
      bv[i] = *(const short8*)(b_base + (fq * 128 + wn * 64 + i * 16 + fr) * 8);
    }
#pragma unroll
    for (int mi = 0; mi < 4; mi++)
#pragma unroll
      for (int ni = 0; ni < 4; ni++)
        acc[mi][ni] = __builtin_amdgcn_mfma_f32_16x16x32_bf16(
            av[mi], bv[ni], acc[mi][ni], 0, 0, 0);
    __syncthreads();
    cur ^= 1;
  }

  // ---- epilogue: bf16 transpose through LDS, coalesced global stores ----
#pragma unroll
  for (int ni = 0; ni < 4; ni++) {
    int col = wn * 64 + ni * 16 + fr;
#pragma unroll
    for (int mi = 0; mi < 4; mi++) {
      int rw = wm * 64 + mi * 16 + fq * 4;
      unsigned lo = (unsigned)f2bf(acc[mi][ni][0]) |
                    ((unsigned)f2bf(acc[mi][ni][1]) << 16);
      unsigned hi = (unsigned)f2bf(acc[mi][ni][2]) |
                    ((unsigned)f2bf(acc[mi][ni][3]) << 16);
      uint2 pk; pk.x = lo; pk.y = hi;
      *(uint2*)((char*)SH + ep_swz(col, rw)) = pk;
    }
  }
  __syncthreads();
  short* Pp = P + (long long)bz * B_DIM * H_DIM;
#pragma unroll
  for (int h = 0; h < 8; ++h) {
    int chunk = tid + h * 256;        // 2048 chunks = 128 rows x 16 colblocks
    int rr = chunk >> 4;
    int j = chunk & 15;
    short8 o;
#pragma unroll
    for (int k = 0; k < 8; ++k) {
      o[k] = *(const short*)((char*)SH + ep_swz(j * 8 + k, rr));
    }
    *(short8*)(Pp + (long long)(bm * 128 + rr) * H_DIM + bn * 128 + j * 8) = o;
  }
}

// Fused: per-row split-K reduce + bias + tanh + hidden write (nontemporal,
// never re-read on-device) + one-hot select + Wy dot + sigmoid + per-row
// BCE term atomically accumulated into errOut (zeroed via hipMemsetAsync).
__global__ __launch_bounds__(256) void fuse_row(
    const short* __restrict__ P, const float* __restrict__ bt,
    const float* __restrict__ bx, const float* __restrict__ Y,
    const float* __restrict__ truth, const float* __restrict__ Wy,
    const float* __restrict__ by, float* __restrict__ predOut,
    float* __restrict__ hidden, float* __restrict__ errOut, int S) {
  const int b = blockIdx.x;
  const int tid = threadIdx.x;
  __shared__ int s_cnt;
  __shared__ int s_idx[8];
  __shared__ float s_val[8];
  __shared__ float s_red[4];
  if (tid == 0) s_cnt = 0;

  const int c = tid * 4;
  float s0 = 0.f, s1 = 0.f, s2 = 0.f, s3 = 0.f;
  for (int z = 0; z < S; ++z) {
    const short* Pr = P + ((long long)z * B_DIM + b) * H_DIM + c;
    uint2 u = *(const uint2*)Pr;
    s0 += bf2f((unsigned short)(u.x & 0xffff));
    s1 += bf2f((unsigned short)(u.x >> 16));
    s2 += bf2f((unsigned short)(u.y & 0xffff));
    s3 += bf2f((unsigned short)(u.y >> 16));
  }
  float4 bt4 = *(const float4*)(bt + c);
  float4 bx4 = *(const float4*)(bx + c);
  float h0 = tanhf(s0 + bt4.x + bx4.x);
  float h1 = tanhf(s1 + bt4.y + bx4.y);
  float h2 = tanhf(s2 + bt4.z + bx4.z);
  float h3 = tanhf(s3 + bt4.w + bx4.w);
  float* Hr = hidden + (long long)b * H_DIM + c;  // base unaligned -> scalar
  __builtin_nontemporal_store(h0, Hr + 0);
  __builtin_nontemporal_store(h1, Hr + 1);
  __builtin_nontemporal_store(h2, Hr + 2);
  __builtin_nontemporal_store(h3, Hr + 3);

  __syncthreads();  // covers s_cnt init
  const float4* Yr = (const float4*)(Y + (long long)b * NQ_DIM);
#pragma unroll
  for (int hh = 0; hh < NQ_DIM / 4 / 256; ++hh) {
    int j = tid + hh * 256;
    float4 v = Yr[j];
    if (v.x != 0.0f) { int p = atomicAdd(&s_cnt, 1); if (p < 8) { s_idx[p] = 4 * j;     s_val[p] = v.x; } }
    if (v.y != 0.0f) { int p = atomicAdd(&s_cnt, 1); if (p < 8) { s_idx[p] = 4 * j + 1; s_val[p] = v.y; } }
    if (v.z != 0.0f) { int p = atomicAdd(&s_cnt, 1); if (p < 8) { s_idx[p] = 4 * j + 2; s_val[p] = v.z; } }
    if (v.w != 0.0f) { int p = atomicAdd(&s_cnt, 1); if (p < 8) { s_idx[p] = 4 * j + 3; s_val[p] = v.w; } }
  }
  __syncthreads();
  int cnt = s_cnt < 8 ? s_cnt : 8;
  float predv = 0.0f;
  for (int it = 0; it < cnt; ++it) {
    int q = s_idx[it];
    float4 w = *(const float4*)(Wy + (long long)q * H_DIM + c);
    float part = h0 * w.x + h1 * w.y + h2 * w.z + h3 * w.w;
#pragma unroll
    for (int off = 32; off > 0; off >>= 1) part += __shfl_down(part, off, 64);
    if ((tid & 63) == 0) s_red[tid >> 6] = part;
    __syncthreads();
    if (tid == 0) {
      float z = s_red[0] + s_red[1] + s_red[2] + s_red[3] + by[q];
      float p = 1.0f / (1.0f + expf(-z));
      predv += s_val[it] * p;
    }
    __syncthreads();
  }
  if (tid == 0) {
    predOut[b] = predv;
    float t = truth[b];
    float lp = fmaxf(logf(predv), -100.0f);
    float l1p = fmaxf(log1pf(-predv), -100.0f);
    atomicAdd(errOut, -(t * lp + (1.0f - t) * l1p));
  }
}

extern "C" void kernel_launch(void* const* d_in, const int* in_sizes, int n_in,
                              void* d_out, int out_size, void* d_ws, size_t ws_size,
                              hipStream_t stream) {
  (void)in_sizes; (void)n_in; (void)out_size;
  const float* state  = (const float*)d_in[0];
  const float* inputX = (const float*)d_in[1];
  const float* inputY = (const float*)d_in[2];
  const float* truth  = (const float*)d_in[3];
  const float* W_t    = (const float*)d_in[4];
  const float* b_t    = (const float*)d_in[5];
  const float* W_x    = (const float*)d_in[6];
  const float* b_x    = (const float*)d_in[7];
  const float* W_y    = (const float*)d_in[8];
  const float* b_y    = (const float*)d_in[9];

  const size_t XC_B = (size_t)B_DIM * K_DIM * 2;   // 41.9 MB
  const size_t WC_B = (size_t)H_DIM * K_DIM * 2;   // 10.5 MB
  const size_t PART = (size_t)B_DIM * H_DIM * 2;   // 8.4 MB per split (bf16)

  int S = 1;
  if (ws_size >= XC_B + WC_B + 4 * PART + 16384) S = 4;
  else if (ws_size >= XC_B + WC_B + 2 * PART + 16384) S = 2;

  short* Xc = (short*)d_ws;
  short* Wc = (short*)((char*)d_ws + XC_B);
  short* P  = (short*)((char*)d_ws + XC_B + WC_B);

  float* predOut = (float*)d_out;             // [0 .. 4095]
  float* errOut  = predOut + B_DIM;           // [4096]
  float* hidden  = predOut + B_DIM + 1;       // [4097 ..]

  cast_v4<<<(B_DIM / 128 + H_DIM / 128) * (NKT / 4), 256, 0, stream>>>(
      state, inputX, W_t, W_x, Xc, Wc);

  gemm_splitk<<<256 * S, 256, 0, stream>>>(Xc, Wc, P, NKT / S);

  hipMemsetAsync(errOut, 0, sizeof(float), stream);
  fuse_row<<<B_DIM, 256, 0, stream>>>(P, b_t, b_x, inputY, truth, W_y, b_y,
                                      predOut, hidden, errOut, S);
}

// Round 14
// 139.467 us; speedup vs baseline: 1.0023x; 1.0023x over previous
//
#include <hip/hip_runtime.h>
#include <stdint.h>
#include <math.h>

#define B_DIM 4096
#define H_DIM 1024
#define NI_DIM 4096
#define NQ_DIM 2048
#define K_DIM 5120   // H + NI
#define NKT 160      // K_DIM / 32

typedef __attribute__((ext_vector_type(8))) short short8;
typedef __attribute__((ext_vector_type(4))) float f32x4;

__device__ __forceinline__ unsigned short f2bf(float f) {
  unsigned u = __float_as_uint(f);
  u += 0x7FFFu + ((u >> 16) & 1u);  // round-to-nearest-even
  return (unsigned short)(u >> 16);
}
__device__ __forceinline__ float bf2f(unsigned short s) {
  return __uint_as_float(((unsigned)s) << 16);
}
__device__ __forceinline__ unsigned pkbf(float a, float b) {
  unsigned r;
  asm("v_cvt_pk_bf16_f32 %0, %1, %2" : "=v"(r) : "v"(a), "v"(b));
  return r;
}

__device__ __forceinline__ void gload_lds16(const void* g, void* l) {
  __builtin_amdgcn_global_load_lds(
      (__attribute__((address_space(1))) void*)(uintptr_t)g,
      (__attribute__((address_space(3))) void*)l, 16, 0, 0);
}

// fp32 -> bf16 cast into staged-tile layout with NONTEMPORAL wide stores.
// R13 PROVED the RFO theory: NT stores dropped this kernel 47 -> ~15us
// (write-allocate read-for-ownership on the 51MB output was the wall).
// NT is ONLY safe on wide coalesced stores (16B short8) -- scalar NT
// stores caused 16x write amplification in fuse_row (R13). DO NOT TOUCH.
__global__ __launch_bounds__(256) void cast_v4(
    const float* __restrict__ X0, const float* __restrict__ X1,
    const float* __restrict__ W0, const float* __restrict__ W1,
    short* __restrict__ Xc, short* __restrict__ Wc) {
  __shared__ __align__(16) short lds[16384];  // 2048 chunks x 8 shorts
  int bt = blockIdx.x;
  const float *s0, *s1;
  short* dst;
  if (bt < (B_DIM / 128) * (NKT / 4)) { s0 = X0; s1 = X1; dst = Xc; }
  else { bt -= (B_DIM / 128) * (NKT / 4); s0 = W0; s1 = W1; dst = Wc; }
  const int rowTile = bt / (NKT / 4);
  const int K0 = (bt % (NKT / 4)) * 4;       // first kt of this block
  const float* src;
  int cols, colBase;
  if (K0 < 32) { src = s0; cols = 1024; colBase = K0 * 32; }
  else         { src = s1; cols = 4096; colBase = (K0 - 32) * 32; }
  const int tid = threadIdx.x;
  const int kc = tid & 31;      // float4 col chunk within 128 cols
  const int r0 = tid >> 5;      // starting row (8 rows per pass)
#pragma unroll
  for (int i = 0; i < 16; ++i) {
    int r = r0 + i * 8;
    float4 v = *(const float4*)(src +
        (long long)(rowTile * 128 + r) * cols + colBase + kc * 4);
    uint2 o;
    o.x = pkbf(v.x, v.y);
    o.y = pkbf(v.z, v.w);
    int l = (kc >> 1) * 128 + r;          // logical chunk (s16*128 + r)
    int p = l ^ ((l >> 7) & 7);           // physical (bank-spread)
    *(uint2*)(&lds[p * 8 + (kc & 1) * 4]) = o;
  }
  __syncthreads();
  short* dbase = dst + ((long long)rowTile * NKT + K0) * 4096;
#pragma unroll
  for (int i = 0; i < 8; ++i) {
    int c = tid + i * 256;
    int p = c ^ ((c >> 7) & 7);
    __builtin_nontemporal_store(*(const short8*)(&lds[p * 8]),
                                (short8*)(dbase + c * 8));
  }
}

// LDS byte-swizzle for the epilogue transpose buffer [col][row] bf16.
__device__ __forceinline__ int ep_swz(int col, int rw) {
  int byte = col * 256 + rw * 2;
  byte ^= ((col ^ (col >> 3)) & 7) << 4;   // spread banks, keeps 8B align
  return byte;
}

// Split-K GEMM (proven: 46.5us, 923 TF, MfmaUtil 39%, conflicts
// epilogue-only). 128x128 tile, BK=32, 4 waves (2x2), dbuf LDS via
// global_load_lds w=16 on staged-tile Xc/Wc; bf16 partials via
// LDS-transposed coalesced epilogue. DO NOT TOUCH (R4/R10/R11/R12 all
// lost to this structure).
__global__ __launch_bounds__(256, 4) void gemm_splitk(
    const short* __restrict__ Xc, const short* __restrict__ Wc,
    short* __restrict__ P, int ntk) {
  __shared__ __align__(16) short SH[16384];  // A dbuf 16KB | B dbuf 16KB
  const int tid = threadIdx.x;
  const int lane = tid & 63;
  const int wid = tid >> 6;
  const int wm = wid >> 1, wn = wid & 1;
  const int fr = lane & 15, fq = lane >> 4;

  const int nwg = gridDim.x;
  const int orig = blockIdx.x;
  const int cpx = nwg >> 3;
  const int swz = (orig & 7) * cpx + (orig >> 3);
  const int bz = swz >> 8;
  const int bm = (swz >> 3) & 31;
  const int bn = swz & 7;
  const int kt0 = bz * ntk;

  const int c0 = tid, c1 = tid + 256;
  const short* gA = Xc + (((long long)bm * NKT + kt0) << 12);  // *4096 shorts
  const short* gB = Wc + (((long long)bn * NKT + kt0) << 12);

  f32x4 acc[4][4] = {};

  gload_lds16(gA + c0 * 8, &SH[c0 * 8]);
  gload_lds16(gA + c1 * 8, &SH[c1 * 8]);
  gload_lds16(gB + c0 * 8, &SH[8192 + c0 * 8]);
  gload_lds16(gB + c1 * 8, &SH[8192 + c1 * 8]);
  __syncthreads();

  int cur = 0;
  for (int t = 0; t < ntk; ++t) {
    if (t + 1 < ntk) {
      const short* nA = gA + (long long)(t + 1) * 4096;
      const short* nB = gB + (long long)(t + 1) * 4096;
      short* lA = &SH[(cur ^ 1) * 4096];
      short* lB = &SH[8192 + (cur ^ 1) * 4096];
      gload_lds16(nA + c0 * 8, lA + c0 * 8);
      gload_lds16(nA + c1 * 8, lA + c1 * 8);
      gload_lds16(nB + c0 * 8, lB + c0 * 8);
      gload_lds16(nB + c1 * 8, lB + c1 * 8);
    }
    const short* a_base = &SH[cur * 4096];
    const short* b_base = &SH[8192 + cur * 4096];
    short8 av[4], bv[4];
#pragma unroll
    for (int i = 0; i < 4; i++) {
      // [slot=fq][row = w*64 + i*16 + fr][8] -> conflict-free granules
      av[i] = *(const short8*)(a_base + (fq * 128 + wm * 64 + i * 16 + fr) * 8);
      bv[i] = *(const short8*)(b_base + (fq * 128 + wn * 64 + i * 16 + fr) * 8);
    }
#pragma unroll
    for (int mi = 0; mi < 4; mi++)
#pragma unroll
      for (int ni = 0; ni < 4; ni++)
        acc[mi][ni] = __builtin_amdgcn_mfma_f32_16x16x32_bf16(
            av[mi], bv[ni], acc[mi][ni], 0, 0, 0);
    __syncthreads();
    cur ^= 1;
  }

  // ---- epilogue: bf16 transpose through LDS, coalesced global stores ----
#pragma unroll
  for (int ni = 0; ni < 4; ni++) {
    int col = wn * 64 + ni * 16 + fr;
#pragma unroll
    for (int mi = 0; mi < 4; mi++) {
      int rw = wm * 64 + mi * 16 + fq * 4;
      unsigned lo = (unsigned)f2bf(acc[mi][ni][0]) |
                    ((unsigned)f2bf(acc[mi][ni][1]) << 16);
      unsigned hi = (unsigned)f2bf(acc[mi][ni][2]) |
                    ((unsigned)f2bf(acc[mi][ni][3]) << 16);
      uint2 pk; pk.x = lo; pk.y = hi;
      *(uint2*)((char*)SH + ep_swz(col, rw)) = pk;
    }
  }
  __syncthreads();
  short* Pp = P + (long long)bz * B_DIM * H_DIM;
#pragma unroll
  for (int h = 0; h < 8; ++h) {
    int chunk = tid + h * 256;        // 2048 chunks = 128 rows x 16 colblocks
    int rr = chunk >> 4;
    int j = chunk & 15;
    short8 o;
#pragma unroll
    for (int k = 0; k < 8; ++k) {
      o[k] = *(const short*)((char*)SH + ep_swz(j * 8 + k, rr));
    }
    *(short8*)(Pp + (long long)(bm * 128 + rr) * H_DIM + bn * 128 + j * 8) = o;
  }
}

// Fused: per-row split-K reduce + bias + tanh + hidden write (PLAIN
// stores -- R13: scalar NT stores caused 16x write amplification) +
// one-hot select + Wy dot + sigmoid + BCE atomicAdd into errOut.
__global__ __launch_bounds__(256) void fuse_row(
    const short* __restrict__ P, const float* __restrict__ bt,
    const float* __restrict__ bx, const float* __restrict__ Y,
    const float* __restrict__ truth, const float* __restrict__ Wy,
    const float* __restrict__ by, float* __restrict__ predOut,
    float* __restrict__ hidden, float* __restrict__ errOut, int S) {
  const int b = blockIdx.x;
  const int tid = threadIdx.x;
  __shared__ int s_cnt;
  __shared__ int s_idx[8];
  __shared__ float s_val[8];
  __shared__ float s_red[4];
  if (tid == 0) s_cnt = 0;

  const int c = tid * 4;
  float s0 = 0.f, s1 = 0.f, s2 = 0.f, s3 = 0.f;
  for (int z = 0; z < S; ++z) {
    const short* Pr = P + ((long long)z * B_DIM + b) * H_DIM + c;
    uint2 u = *(const uint2*)Pr;
    s0 += bf2f((unsigned short)(u.x & 0xffff));
    s1 += bf2f((unsigned short)(u.x >> 16));
    s2 += bf2f((unsigned short)(u.y & 0xffff));
    s3 += bf2f((unsigned short)(u.y >> 16));
  }
  float4 bt4 = *(const float4*)(bt + c);
  float4 bx4 = *(const float4*)(bx + c);
  float h0 = tanhf(s0 + bt4.x + bx4.x);
  float h1 = tanhf(s1 + bt4.y + bx4.y);
  float h2 = tanhf(s2 + bt4.z + bx4.z);
  float h3 = tanhf(s3 + bt4.w + bx4.w);
  float* Hr = hidden + (long long)b * H_DIM + c;  // base unaligned -> scalar
  Hr[0] = h0; Hr[1] = h1; Hr[2] = h2; Hr[3] = h3;

  __syncthreads();  // covers s_cnt init
  const float4* Yr = (const float4*)(Y + (long long)b * NQ_DIM);
#pragma unroll
  for (int hh = 0; hh < NQ_DIM / 4 / 256; ++hh) {
    int j = tid + hh * 256;
    float4 v = Yr[j];
    if (v.x != 0.0f) { int p = atomicAdd(&s_cnt, 1); if (p < 8) { s_idx[p] = 4 * j;     s_val[p] = v.x; } }
    if (v.y != 0.0f) { int p = atomicAdd(&s_cnt, 1); if (p < 8) { s_idx[p] = 4 * j + 1; s_val[p] = v.y; } }
    if (v.z != 0.0f) { int p = atomicAdd(&s_cnt, 1); if (p < 8) { s_idx[p] = 4 * j + 2; s_val[p] = v.z; } }
    if (v.w != 0.0f) { int p = atomicAdd(&s_cnt, 1); if (p < 8) { s_idx[p] = 4 * j + 3; s_val[p] = v.w; } }
  }
  __syncthreads();
  int cnt = s_cnt < 8 ? s_cnt : 8;
  float predv = 0.0f;
  for (int it = 0; it < cnt; ++it) {
    int q = s_idx[it];
    float4 w = *(const float4*)(Wy + (long long)q * H_DIM + c);
    float part = h0 * w.x + h1 * w.y + h2 * w.z + h3 * w.w;
#pragma unroll
    for (int off = 32; off > 0; off >>= 1) part += __shfl_down(part, off, 64);
    if ((tid & 63) == 0) s_red[tid >> 6] = part;
    __syncthreads();
    if (tid == 0) {
      float z = s_red[0] + s_red[1] + s_red[2] + s_red[3] + by[q];
      float p = 1.0f / (1.0f + expf(-z));
      predv += s_val[it] * p;
    }
    __syncthreads();
  }
  if (tid == 0) {
    predOut[b] = predv;
    float t = truth[b];
    float lp = fmaxf(logf(predv), -100.0f);
    float l1p = fmaxf(log1pf(-predv), -100.0f);
    atomicAdd(errOut, -(t * lp + (1.0f - t) * l1p));
  }
}

extern "C" void kernel_launch(void* const* d_in, const int* in_sizes, int n_in,
                              void* d_out, int out_size, void* d_ws, size_t ws_size,
                              hipStream_t stream) {
  (void)in_sizes; (void)n_in; (void)out_size;
  const float* state  = (const float*)d_in[0];
  const float* inputX = (const float*)d_in[1];
  const float* inputY = (const float*)d_in[2];
  const float* truth  = (const float*)d_in[3];
  const float* W_t    = (const float*)d_in[4];
  const float* b_t    = (const float*)d_in[5];
  const float* W_x    = (const float*)d_in[6];
  const float* b_x    = (const float*)d_in[7];
  const float* W_y    = (const float*)d_in[8];
  const float* b_y    = (const float*)d_in[9];

  const size_t XC_B = (size_t)B_DIM * K_DIM * 2;   // 41.9 MB
  const size_t WC_B = (size_t)H_DIM * K_DIM * 2;   // 10.5 MB
  const size_t PART = (size_t)B_DIM * H_DIM * 2;   // 8.4 MB per split (bf16)

  int S = 1;
  if (ws_size >= XC_B + WC_B + 4 * PART + 16384) S = 4;
  else if (ws_size >= XC_B + WC_B + 2 * PART + 16384) S = 2;

  short* Xc = (short*)d_ws;
  short* Wc = (short*)((char*)d_ws + XC_B);
  short* P  = (short*)((char*)d_ws + XC_B + WC_B);

  float* predOut = (float*)d_out;             // [0 .. 4095]
  float* errOut  = predOut + B_DIM;           // [4096]
  float* hidden  = predOut + B_DIM + 1;       // [4097 ..]

  cast_v4<<<(B_DIM / 128 + H_DIM / 128) * (NKT / 4), 256, 0, stream>>>(
      state, inputX, W_t, W_x, Xc, Wc);

  gemm_splitk<<<256 * S, 256, 0, stream>>>(Xc, Wc, P, NKT / S);

  hipMemsetAsync(errOut, 0, sizeof(float), stream);
  fuse_row<<<B_DIM, 256, 0, stream>>>(P, b_t, b_x, inputY, truth, W_y, b_y,
                                      predOut, hidden, errOut, S);
}

// Round 15
// 101.908 us; speedup vs baseline: 1.3717x; 1.3686x over previous
//
#include <hip/hip_runtime.h>
#include <stdint.h>
#include <math.h>

#define B_DIM 4096
#define H_DIM 1024
#define NI_DIM 4096
#define NQ_DIM 2048
#define K_DIM 5120   // H + NI
#define NKT 160      // K_DIM / 32

typedef __attribute__((ext_vector_type(8))) short short8;
typedef __attribute__((ext_vector_type(4))) float f32x4;

__device__ __forceinline__ unsigned short f2bf(float f) {
  unsigned u = __float_as_uint(f);
  u += 0x7FFFu + ((u >> 16) & 1u);  // round-to-nearest-even
  return (unsigned short)(u >> 16);
}
__device__ __forceinline__ float bf2f(unsigned short s) {
  return __uint_as_float(((unsigned)s) << 16);
}
__device__ __forceinline__ unsigned pkbf(float a, float b) {
  unsigned r;
  asm("v_cvt_pk_bf16_f32 %0, %1, %2" : "=v"(r) : "v"(a), "v"(b));
  return r;
}

__device__ __forceinline__ void gload_lds16(const void* g, void* l) {
  __builtin_amdgcn_global_load_lds(
      (__attribute__((address_space(1))) void*)(uintptr_t)g,
      (__attribute__((address_space(3))) void*)l, 16, 0, 0);
}

// fp32 -> bf16 cast into staged-tile layout with NONTEMPORAL wide stores.
// R13/R14 PROVED: NT wide stores dropped this kernel 47 -> ~15us (the
// invariant wall across 5 variants was write-allocate RFO on the 51MB
// output). NT only on wide coalesced 16B stores. DO NOT TOUCH.
__global__ __launch_bounds__(256) void cast_v4(
    const float* __restrict__ X0, const float* __restrict__ X1,
    const float* __restrict__ W0, const float* __restrict__ W1,
    short* __restrict__ Xc, short* __restrict__ Wc) {
  __shared__ __align__(16) short lds[16384];  // 2048 chunks x 8 shorts
  int bt = blockIdx.x;
  const float *s0, *s1;
  short* dst;
  if (bt < (B_DIM / 128) * (NKT / 4)) { s0 = X0; s1 = X1; dst = Xc; }
  else { bt -= (B_DIM / 128) * (NKT / 4); s0 = W0; s1 = W1; dst = Wc; }
  const int rowTile = bt / (NKT / 4);
  const int K0 = (bt % (NKT / 4)) * 4;       // first kt of this block
  const float* src;
  int cols, colBase;
  if (K0 < 32) { src = s0; cols = 1024; colBase = K0 * 32; }
  else         { src = s1; cols = 4096; colBase = (K0 - 32) * 32; }
  const int tid = threadIdx.x;
  const int kc = tid & 31;      // float4 col chunk within 128 cols
  const int r0 = tid >> 5;      // starting row (8 rows per pass)
#pragma unroll
  for (int i = 0; i < 16; ++i) {
    int r = r0 + i * 8;
    float4 v = *(const float4*)(src +
        (long long)(rowTile * 128 + r) * cols + colBase + kc * 4);
    uint2 o;
    o.x = pkbf(v.x, v.y);
    o.y = pkbf(v.z, v.w);
    int l = (kc >> 1) * 128 + r;          // logical chunk (s16*128 + r)
    int p = l ^ ((l >> 7) & 7);           // physical (bank-spread)
    *(uint2*)(&lds[p * 8 + (kc & 1) * 4]) = o;
  }
  __syncthreads();
  short* dbase = dst + ((long long)rowTile * NKT + K0) * 4096;
#pragma unroll
  for (int i = 0; i < 8; ++i) {
    int c = tid + i * 256;
    int p = c ^ ((c >> 7) & 7);
    __builtin_nontemporal_store(*(const short8*)(&lds[p * 8]),
                                (short8*)(dbase + c * 8));
  }
}

// LDS byte-swizzle for the epilogue transpose buffer [col][row] bf16.
__device__ __forceinline__ int ep_swz(int col, int rw) {
  int byte = col * 256 + rw * 2;
  byte ^= ((col ^ (col >> 3)) & 7) << 4;   // spread banks, keeps 8B align
  return byte;
}

// Split-K GEMM (proven: 46.5us, 923 TF, MfmaUtil 39%). DO NOT TOUCH
// (R4/R10/R11/R12 structural variants all lost to this).
__global__ __launch_bounds__(256, 4) void gemm_splitk(
    const short* __restrict__ Xc, const short* __restrict__ Wc,
    short* __restrict__ P, int ntk) {
  __shared__ __align__(16) short SH[16384];  // A dbuf 16KB | B dbuf 16KB
  const int tid = threadIdx.x;
  const int lane = tid & 63;
  const int wid = tid >> 6;
  const int wm = wid >> 1, wn = wid & 1;
  const int fr = lane & 15, fq = lane >> 4;

  const int nwg = gridDim.x;
  const int orig = blockIdx.x;
  const int cpx = nwg >> 3;
  const int swz = (orig & 7) * cpx + (orig >> 3);
  const int bz = swz >> 8;
  const int bm = (swz >> 3) & 31;
  const int bn = swz & 7;
  const int kt0 = bz * ntk;

  const int c0 = tid, c1 = tid + 256;
  const short* gA = Xc + (((long long)bm * NKT + kt0) << 12);  // *4096 shorts
  const short* gB = Wc + (((long long)bn * NKT + kt0) << 12);

  f32x4 acc[4][4] = {};

  gload_lds16(gA + c0 * 8, &SH[c0 * 8]);
  gload_lds16(gA + c1 * 8, &SH[c1 * 8]);
  gload_lds16(gB + c0 * 8, &SH[8192 + c0 * 8]);
  gload_lds16(gB + c1 * 8, &SH[8192 + c1 * 8]);
  __syncthreads();

  int cur = 0;
  for (int t = 0; t < ntk; ++t) {
    if (t + 1 < ntk) {
      const short* nA = gA + (long long)(t + 1) * 4096;
      const short* nB = gB + (long long)(t + 1) * 4096;
      short* lA = &SH[(cur ^ 1) * 4096];
      short* lB = &SH[8192 + (cur ^ 1) * 4096];
      gload_lds16(nA + c0 * 8, lA + c0 * 8);
      gload_lds16(nA + c1 * 8, lA + c1 * 8);
      gload_lds16(nB + c0 * 8, lB + c0 * 8);
      gload_lds16(nB + c1 * 8, lB + c1 * 8);
    }
    const short* a_base = &SH[cur * 4096];
    const short* b_base = &SH[8192 + cur * 4096];
    short8 av[4], bv[4];
#pragma unroll
    for (int i = 0; i < 4; i++) {
      // [slot=fq][row = w*64 + i*16 + fr][8] -> conflict-free granules
      av[i] = *(const short8*)(a_base + (fq * 128 + wm * 64 + i * 16 + fr) * 8);
      bv[i] = *(const short8*)(b_base + (fq * 128 + wn * 64 + i * 16 + fr) * 8);
    }
#pragma unroll
    for (int mi = 0; mi < 4; mi++)
#pragma unroll
      for (int ni = 0; ni < 4; ni++)
        acc[mi][ni] = __builtin_amdgcn_mfma_f32_16x16x32_bf16(
            av[mi], bv[ni], acc[mi][ni], 0, 0, 0);
    __syncthreads();
    cur ^= 1;
  }

  // ---- epilogue: bf16 transpose through LDS, coalesced global stores ----
#pragma unroll
  for (int ni = 0; ni < 4; ni++) {
    int col = wn * 64 + ni * 16 + fr;
#pragma unroll
    for (int mi = 0; mi < 4; mi++) {
      int rw = wm * 64 + mi * 16 + fq * 4;
      unsigned lo = (unsigned)f2bf(acc[mi][ni][0]) |
                    ((unsigned)f2bf(acc[mi][ni][1]) << 16);
      unsigned hi = (unsigned)f2bf(acc[mi][ni][2]) |
                    ((unsigned)f2bf(acc[mi][ni][3]) << 16);
      uint2 pk; pk.x = lo; pk.y = hi;
      *(uint2*)((char*)SH + ep_swz(col, rw)) = pk;
    }
  }
  __syncthreads();
  short* Pp = P + (long long)bz * B_DIM * H_DIM;
#pragma unroll
  for (int h = 0; h < 8; ++h) {
    int chunk = tid + h * 256;        // 2048 chunks = 128 rows x 16 colblocks
    int rr = chunk >> 4;
    int j = chunk & 15;
    short8 o;
#pragma unroll
    for (int k = 0; k < 8; ++k) {
      o[k] = *(const short*)((char*)SH + ep_swz(j * 8 + k, rr));
    }
    *(short8*)(Pp + (long long)(bm * 128 + rr) * H_DIM + bn * 128 + j * 8) = o;
  }
}

// Fused: per-row split-K reduce + bias + tanh + hidden write + one-hot
// select + Wy dot + sigmoid + per-row BCE into bce[b].
// R14 LESSON: do NOT atomicAdd 4096 blocks into one address -- the
// serialized cross-XCD atomic chain cost ~66us (8->73us). Per-row array
// + separate 1-block reduction is the proven-fast form.
__global__ __launch_bounds__(256) void fuse_row(
    const short* __restrict__ P, const float* __restrict__ bt,
    const float* __restrict__ bx, const float* __restrict__ Y,
    const float* __restrict__ truth, const float* __restrict__ Wy,
    const float* __restrict__ by, float* __restrict__ predOut,
    float* __restrict__ hidden, float* __restrict__ bce, int S) {
  const int b = blockIdx.x;
  const int tid = threadIdx.x;
  __shared__ int s_cnt;
  __shared__ int s_idx[8];
  __shared__ float s_val[8];
  __shared__ float s_red[4];
  if (tid == 0) s_cnt = 0;

  const int c = tid * 4;
  float s0 = 0.f, s1 = 0.f, s2 = 0.f, s3 = 0.f;
  for (int z = 0; z < S; ++z) {
    const short* Pr = P + ((long long)z * B_DIM + b) * H_DIM + c;
    uint2 u = *(const uint2*)Pr;
    s0 += bf2f((unsigned short)(u.x & 0xffff));
    s1 += bf2f((unsigned short)(u.x >> 16));
    s2 += bf2f((unsigned short)(u.y & 0xffff));
    s3 += bf2f((unsigned short)(u.y >> 16));
  }
  float4 bt4 = *(const float4*)(bt + c);
  float4 bx4 = *(const float4*)(bx + c);
  float h0 = tanhf(s0 + bt4.x + bx4.x);
  float h1 = tanhf(s1 + bt4.y + bx4.y);
  float h2 = tanhf(s2 + bt4.z + bx4.z);
  float h3 = tanhf(s3 + bt4.w + bx4.w);
  float* Hr = hidden + (long long)b * H_DIM + c;  // base unaligned -> scalar
  Hr[0] = h0; Hr[1] = h1; Hr[2] = h2; Hr[3] = h3;

  __syncthreads();  // covers s_cnt init
  const float4* Yr = (const float4*)(Y + (long long)b * NQ_DIM);
#pragma unroll
  for (int hh = 0; hh < NQ_DIM / 4 / 256; ++hh) {
    int j = tid + hh * 256;
    float4 v = Yr[j];
    if (v.x != 0.0f) { int p = atomicAdd(&s_cnt, 1); if (p < 8) { s_idx[p] = 4 * j;     s_val[p] = v.x; } }
    if (v.y != 0.0f) { int p = atomicAdd(&s_cnt, 1); if (p < 8) { s_idx[p] = 4 * j + 1; s_val[p] = v.y; } }
    if (v.z != 0.0f) { int p = atomicAdd(&s_cnt, 1); if (p < 8) { s_idx[p] = 4 * j + 2; s_val[p] = v.z; } }
    if (v.w != 0.0f) { int p = atomicAdd(&s_cnt, 1); if (p < 8) { s_idx[p] = 4 * j + 3; s_val[p] = v.w; } }
  }
  __syncthreads();
  int cnt = s_cnt < 8 ? s_cnt : 8;
  float predv = 0.0f;
  for (int it = 0; it < cnt; ++it) {
    int q = s_idx[it];
    float4 w = *(const float4*)(Wy + (long long)q * H_DIM + c);
    float part = h0 * w.x + h1 * w.y + h2 * w.z + h3 * w.w;
#pragma unroll
    for (int off = 32; off > 0; off >>= 1) part += __shfl_down(part, off, 64);
    if ((tid & 63) == 0) s_red[tid >> 6] = part;
    __syncthreads();
    if (tid == 0) {
      float z = s_red[0] + s_red[1] + s_red[2] + s_red[3] + by[q];
      float p = 1.0f / (1.0f + expf(-z));
      predv += s_val[it] * p;
    }
    __syncthreads();
  }
  if (tid == 0) {
    predOut[b] = predv;
    float t = truth[b];
    float lp = fmaxf(logf(predv), -100.0f);
    float l1p = fmaxf(log1pf(-predv), -100.0f);
    bce[b] = -(t * lp + (1.0f - t) * l1p);
  }
}

__global__ __launch_bounds__(256) void reduce_err(
    const float* __restrict__ bce, float* __restrict__ errOut) {
  float s = 0.0f;
  for (int i = threadIdx.x; i < B_DIM; i += 256) s += bce[i];
#pragma unroll
  for (int off = 32; off > 0; off >>= 1) s += __shfl_down(s, off, 64);
  __shared__ float red[4];
  if ((threadIdx.x & 63) == 0) red[threadIdx.x >> 6] = s;
  __syncthreads();
  if (threadIdx.x == 0) errOut[0] = red[0] + red[1] + red[2] + red[3];
}

extern "C" void kernel_launch(void* const* d_in, const int* in_sizes, int n_in,
                              void* d_out, int out_size, void* d_ws, size_t ws_size,
                              hipStream_t stream) {
  (void)in_sizes; (void)n_in; (void)out_size;
  const float* state  = (const float*)d_in[0];
  const float* inputX = (const float*)d_in[1];
  const float* inputY = (const float*)d_in[2];
  const float* truth  = (const float*)d_in[3];
  const float* W_t    = (const float*)d_in[4];
  const float* b_t    = (const float*)d_in[5];
  const float* W_x    = (const float*)d_in[6];
  const float* b_x    = (const float*)d_in[7];
  const float* W_y    = (const float*)d_in[8];
  const float* b_y    = (const float*)d_in[9];

  const size_t XC_B = (size_t)B_DIM * K_DIM * 2;   // 41.9 MB
  const size_t WC_B = (size_t)H_DIM * K_DIM * 2;   // 10.5 MB
  const size_t PART = (size_t)B_DIM * H_DIM * 2;   // 8.4 MB per split (bf16)

  int S = 1;
  if (ws_size >= XC_B + WC_B + 4 * PART + 16384) S = 4;
  else if (ws_size >= XC_B + WC_B + 2 * PART + 16384) S = 2;

  short* Xc = (short*)d_ws;
  short* Wc = (short*)((char*)d_ws + XC_B);
  short* P  = (short*)((char*)d_ws + XC_B + WC_B);
  float* bce = (float*)((char*)d_ws + XC_B + WC_B + (size_t)S * PART);

  float* predOut = (float*)d_out;             // [0 .. 4095]
  float* errOut  = predOut + B_DIM;           // [4096]
  float* hidden  = predOut + B_DIM + 1;       // [4097 ..]

  cast_v4<<<(B_DIM / 128 + H_DIM / 128) * (NKT / 4), 256, 0, stream>>>(
      state, inputX, W_t, W_x, Xc, Wc);

  gemm_splitk<<<256 * S, 256, 0, stream>>>(Xc, Wc, P, NKT / S);

  fuse_row<<<B_DIM, 256, 0, stream>>>(P, b_t, b_x, inputY, truth, W_y, b_y,
                                      predOut, hidden, bce, S);
  reduce_err<<<1, 256, 0, stream>>>(bce, errOut);
}

// Round 16
// 96.190 us; speedup vs baseline: 1.4532x; 1.0594x over previous
//
#include <hip/hip_runtime.h>
#include <stdint.h>
#include <math.h>

#define B_DIM 4096
#define H_DIM 1024
#define NI_DIM 4096
#define NQ_DIM 2048
#define K_DIM 5120   // H + NI
#define NKT 160      // K_DIM / 32

typedef __attribute__((ext_vector_type(8))) short short8;
typedef __attribute__((ext_vector_type(4))) float f32x4;

__device__ __forceinline__ unsigned short f2bf(float f) {
  unsigned u = __float_as_uint(f);
  u += 0x7FFFu + ((u >> 16) & 1u);  // round-to-nearest-even
  return (unsigned short)(u >> 16);
}
__device__ __forceinline__ float bf2f(unsigned short s) {
  return __uint_as_float(((unsigned)s) << 16);
}
__device__ __forceinline__ unsigned pkbf(float a, float b) {
  unsigned r;
  asm("v_cvt_pk_bf16_f32 %0, %1, %2" : "=v"(r) : "v"(a), "v"(b));
  return r;
}

__device__ __forceinline__ void gload_lds16(const void* g, void* l) {
  __builtin_amdgcn_global_load_lds(
      (__attribute__((address_space(1))) void*)(uintptr_t)g,
      (__attribute__((address_space(3))) void*)l, 16, 0, 0);
}

// fp32 -> bf16 cast into staged-tile layout. REGULAR stores (R15 lesson:
// NT stores starve the gemm of L3-resident inputs -> gemm +13.5us; net
// negative. NT is only for never-re-read outputs).
__global__ __launch_bounds__(256) void cast_v4(
    const float* __restrict__ X0, const float* __restrict__ X1,
    const float* __restrict__ W0, const float* __restrict__ W1,
    short* __restrict__ Xc, short* __restrict__ Wc) {
  __shared__ __align__(16) short lds[16384];  // 2048 chunks x 8 shorts
  int bt = blockIdx.x;
  const float *s0, *s1;
  short* dst;
  if (bt < (B_DIM / 128) * (NKT / 4)) { s0 = X0; s1 = X1; dst = Xc; }
  else { bt -= (B_DIM / 128) * (NKT / 4); s0 = W0; s1 = W1; dst = Wc; }
  const int rowTile = bt / (NKT / 4);
  const int K0 = (bt % (NKT / 4)) * 4;       // first kt of this block
  const float* src;
  int cols, colBase;
  if (K0 < 32) { src = s0; cols = 1024; colBase = K0 * 32; }
  else         { src = s1; cols = 4096; colBase = (K0 - 32) * 32; }
  const int tid = threadIdx.x;
  const int kc = tid & 31;      // float4 col chunk within 128 cols
  const int r0 = tid >> 5;      // starting row (8 rows per pass)
#pragma unroll
  for (int i = 0; i < 16; ++i) {
    int r = r0 + i * 8;
    float4 v = *(const float4*)(src +
        (long long)(rowTile * 128 + r) * cols + colBase + kc * 4);
    uint2 o;
    o.x = pkbf(v.x, v.y);
    o.y = pkbf(v.z, v.w);
    int l = (kc >> 1) * 128 + r;          // logical chunk (s16*128 + r)
    int p = l ^ ((l >> 7) & 7);           // physical (bank-spread)
    *(uint2*)(&lds[p * 8 + (kc & 1) * 4]) = o;
  }
  __syncthreads();
  short* dbase = dst + ((long long)rowTile * NKT + K0) * 4096;
#pragma unroll
  for (int i = 0; i < 8; ++i) {
    int c = tid + i * 256;
    int p = c ^ ((c >> 7) & 7);
    *(short8*)(dbase + c * 8) = *(const short8*)(&lds[p * 8]);
  }
}

// LDS byte-swizzle for the 256x256 epilogue transpose [col][row] bf16.
__device__ __forceinline__ int ep_swz(int col, int rw) {
  int byte = col * 512 + rw * 2;           // [col 0..255][row 0..255]
  byte ^= ((col ^ (col >> 3)) & 7) << 4;   // spread banks, keeps 8B align
  return byte;
}

// 256x256 split-K GEMM, faithful m201-style fine-phase schedule:
// BK=32 K-tiles, 4 LDS slots x 32KB (depth-3-ahead staging), 2 phases
// per K-tile, each phase = {ds_read subtile (8 or 4 b128) || stage 2
// gloads -> s_barrier -> lgkmcnt(0) -> setprio(1) 16 MFMA setprio(0) ->
// s_barrier}; counted vmcnt(8) ONCE per K-tile (end of phase B), never
// 0 until the tail. WAR: stage(T+3) writes slot (T-1)&3 whose readers
// finished at phase-B(T-1)'s lgkm(0) + closing barrier.
// ds_read pattern is the proven conflict-free [slot][row][8] granules.
__global__ __launch_bounds__(512, 2) void gemm_8ph(
    const short* __restrict__ Xc, const short* __restrict__ Wc,
    short* __restrict__ P, int NT) {   // NT = (NKT/S) 32-k tiles per block
  __shared__ __align__(16) short SH[65536];  // 4 slots x 16384 shorts
  const int tid = threadIdx.x;
  const int lane = tid & 63;
  const int wid = tid >> 6;            // 0..7
  const int wr = wid >> 2, wc = wid & 3;
  const int fr = lane & 15, fq = lane >> 4;

  const int nwg = gridDim.x;           // 64*S, divisible by 8
  const int orig = blockIdx.x;
  const int cpx = nwg >> 3;
  const int swz = (orig & 7) * cpx + (orig >> 3);
  const int bz = swz >> 6;             // split index
  const int bm = (swz >> 2) & 15;      // 256-row tile
  const int bn = swz & 3;              // 256-col tile
  const int kt0 = bz * NT;

  const short* gA0 = Xc + ((long long)((bm * 2 + 0) * NKT + kt0) << 12);
  const short* gA1 = Xc + ((long long)((bm * 2 + 1) * NKT + kt0) << 12);
  const short* gB0 = Wc + ((long long)((bn * 2 + 0) * NKT + kt0) << 12);
  const short* gB1 = Wc + ((long long)((bn * 2 + 1) * NKT + kt0) << 12);

  const int t8 = tid * 8;

#define STAGE_A(tt)                                                      \
  {                                                                      \
    long long o = ((long long)(tt) << 12) + t8;                          \
    short* L = &SH[((tt) & 3) * 16384];                                  \
    gload_lds16(gA0 + o, L + t8);                                        \
    gload_lds16(gA1 + o, L + 4096 + t8);                                 \
  }
#define STAGE_B(tt)                                                      \
  {                                                                      \
    long long o = ((long long)(tt) << 12) + t8;                          \
    short* L = &SH[((tt) & 3) * 16384];                                  \
    gload_lds16(gB0 + o, L + 8192 + t8);                                 \
    gload_lds16(gB1 + o, L + 12288 + t8);                                \
  }

  f32x4 acc[8][4] = {};

  // prologue: stage tiles 0..2 (12 loads/thread, FIFO), wait tile 0.
  STAGE_A(0); STAGE_B(0);
  STAGE_A(1); STAGE_B(1);
  STAGE_A(2); STAGE_B(2);
  asm volatile("s_waitcnt vmcnt(8)" ::: "memory");
  __builtin_amdgcn_s_barrier();

  for (int T = 0; T < NT; ++T) {
    const short* slot = &SH[(T & 3) * 16384];
    const short* aS = slot + wr * 4096;                 // A row-half wr
    const short* bS = slot + 8192 + (wc >> 1) * 4096;   // B row-half
    const int brow = (wc & 1) * 64;

    // ---- phase A: av0-3 + bv0-3 (8 ds_read) || stage A-half of T+3 ----
    short8 a0[4], bv[4];
#pragma unroll
    for (int mi = 0; mi < 4; ++mi)
      a0[mi] = *(const short8*)(aS + (fq * 128 + mi * 16 + fr) * 8);
#pragma unroll
    for (int ni = 0; ni < 4; ++ni)
      bv[ni] = *(const short8*)(bS + (fq * 128 + brow + ni * 16 + fr) * 8);
    if (T + 3 < NT) STAGE_A(T + 3);
    __builtin_amdgcn_s_barrier();
    asm volatile("s_waitcnt lgkmcnt(0)" ::: "memory");
    __builtin_amdgcn_s_setprio(1);
#pragma unroll
    for (int mi = 0; mi < 4; ++mi)
#pragma unroll
      for (int ni = 0; ni < 4; ++ni)
        acc[mi][ni] = __builtin_amdgcn_mfma_f32_16x16x32_bf16(
            a0[mi], bv[ni], acc[mi][ni], 0, 0, 0);
    __builtin_amdgcn_s_setprio(0);
    __builtin_amdgcn_s_barrier();

    // ---- phase B: av4-7 (4 ds_read) || stage B-half of T+3 ----
    short8 a1[4];
#pragma unroll
    for (int mi = 0; mi < 4; ++mi)
      a1[mi] = *(const short8*)(aS + (fq * 128 + (mi + 4) * 16 + fr) * 8);
    if (T + 3 < NT) STAGE_B(T + 3);
    __builtin_amdgcn_s_barrier();
    asm volatile("s_waitcnt lgkmcnt(0)" ::: "memory");
    __builtin_amdgcn_s_setprio(1);
#pragma unroll
    for (int mi = 0; mi < 4; ++mi)
#pragma unroll
      for (int ni = 0; ni < 4; ++ni)
        acc[mi + 4][ni] = __builtin_amdgcn_mfma_f32_16x16x32_bf16(
            a1[mi], bv[ni], acc[mi + 4][ni], 0, 0, 0);
    __builtin_amdgcn_s_setprio(0);
    // end-of-tile wait: tile T+1's 4 loads landed (FIFO-counted).
    if (T + 1 < NT) {
      if (T + 4 <= NT)      asm volatile("s_waitcnt vmcnt(8)" ::: "memory");
      else if (T + 3 == NT) asm volatile("s_waitcnt vmcnt(4)" ::: "memory");
      else                  asm volatile("s_waitcnt vmcnt(0)" ::: "memory");
    }
    __builtin_amdgcn_s_barrier();
  }
#undef STAGE_A
#undef STAGE_B

  // ---- epilogue: bf16 transpose through the 128KB LDS (R11-proven) ----
#pragma unroll
  for (int ni = 0; ni < 4; ++ni) {
    int col = wc * 64 + ni * 16 + fr;
#pragma unroll
    for (int mi = 0; mi < 8; ++mi) {
      int rw = wr * 128 + mi * 16 + fq * 4;
      uint2 pk;
      pk.x = (unsigned)f2bf(acc[mi][ni][0]) |
             ((unsigned)f2bf(acc[mi][ni][1]) << 16);
      pk.y = (unsigned)f2bf(acc[mi][ni][2]) |
             ((unsigned)f2bf(acc[mi][ni][3]) << 16);
      *(uint2*)((char*)SH + ep_swz(col, rw)) = pk;
    }
  }
  __syncthreads();
  short* Pp = P + (long long)bz * B_DIM * H_DIM;
#pragma unroll
  for (int h = 0; h < 16; ++h) {
    int chunk = tid + h * 512;        // 8192 chunks = 256 rows x 32 colblocks
    int rr = chunk >> 5;
    int j = chunk & 31;
    short8 o;
#pragma unroll
    for (int k = 0; k < 8; ++k) {
      o[k] = *(const short*)((char*)SH + ep_swz(j * 8 + k, rr));
    }
    *(short8*)(Pp + (long long)(bm * 256 + rr) * H_DIM + bn * 256 + j * 8) = o;
  }
}

// Fused: per-row split-K reduce + bias + tanh + hidden write + one-hot
// select + Wy dot + sigmoid + per-row BCE into bce[b]. (R14: never
// atomicAdd 4096 blocks into one address -- 66us serialization.)
__global__ __launch_bounds__(256) void fuse_row(
    const short* __restrict__ P, const float* __restrict__ bt,
    const float* __restrict__ bx, const float* __restrict__ Y,
    const float* __restrict__ truth, const float* __restrict__ Wy,
    const float* __restrict__ by, float* __restrict__ predOut,
    float* __restrict__ hidden, float* __restrict__ bce, int S) {
  const int b = blockIdx.x;
  const int tid = threadIdx.x;
  __shared__ int s_cnt;
  __shared__ int s_idx[8];
  __shared__ float s_val[8];
  __shared__ float s_red[4];
  if (tid == 0) s_cnt = 0;

  const int c = tid * 4;
  float s0 = 0.f, s1 = 0.f, s2 = 0.f, s3 = 0.f;
  for (int z = 0; z < S; ++z) {
    const short* Pr = P + ((long long)z * B_DIM + b) * H_DIM + c;
    uint2 u = *(const uint2*)Pr;
    s0 += bf2f((unsigned short)(u.x & 0xffff));
    s1 += bf2f((unsigned short)(u.x >> 16));
    s2 += bf2f((unsigned short)(u.y & 0xffff));
    s3 += bf2f((unsigned short)(u.y >> 16));
  }
  float4 bt4 = *(const float4*)(bt + c);
  float4 bx4 = *(const float4*)(bx + c);
  float h0 = tanhf(s0 + bt4.x + bx4.x);
  float h1 = tanhf(s1 + bt4.y + bx4.y);
  float h2 = tanhf(s2 + bt4.z + bx4.z);
  float h3 = tanhf(s3 + bt4.w + bx4.w);
  float* Hr = hidden + (long long)b * H_DIM + c;  // base unaligned -> scalar
  Hr[0] = h0; Hr[1] = h1; Hr[2] = h2; Hr[3] = h3;

  __syncthreads();  // covers s_cnt init
  const float4* Yr = (const float4*)(Y + (long long)b * NQ_DIM);
#pragma unroll
  for (int hh = 0; hh < NQ_DIM / 4 / 256; ++hh) {
    int j = tid + hh * 256;
    float4 v = Yr[j];
    if (v.x != 0.0f) { int p = atomicAdd(&s_cnt, 1); if (p < 8) { s_idx[p] = 4 * j;     s_val[p] = v.x; } }
    if (v.y != 0.0f) { int p = atomicAdd(&s_cnt, 1); if (p < 8) { s_idx[p] = 4 * j + 1; s_val[p] = v.y; } }
    if (v.z != 0.0f) { int p = atomicAdd(&s_cnt, 1); if (p < 8) { s_idx[p] = 4 * j + 2; s_val[p] = v.z; } }
    if (v.w != 0.0f) { int p = atomicAdd(&s_cnt, 1); if (p < 8) { s_idx[p] = 4 * j + 3; s_val[p] = v.w; } }
  }
  __syncthreads();
  int cnt = s_cnt < 8 ? s_cnt : 8;
  float predv = 0.0f;
  for (int it = 0; it < cnt; ++it) {
    int q = s_idx[it];
    float4 w = *(const float4*)(Wy + (long long)q * H_DIM + c);
    float part = h0 * w.x + h1 * w.y + h2 * w.z + h3 * w.w;
#pragma unroll
    for (int off = 32; off > 0; off >>= 1) part += __shfl_down(part, off, 64);
    if ((tid & 63) == 0) s_red[tid >> 6] = part;
    __syncthreads();
    if (tid == 0) {
      float z = s_red[0] + s_red[1] + s_red[2] + s_red[3] + by[q];
      float p = 1.0f / (1.0f + expf(-z));
      predv += s_val[it] * p;
    }
    __syncthreads();
  }
  if (tid == 0) {
    predOut[b] = predv;
    float t = truth[b];
    float lp = fmaxf(logf(predv), -100.0f);
    float l1p = fmaxf(log1pf(-predv), -100.0f);
    bce[b] = -(t * lp + (1.0f - t) * l1p);
  }
}

__global__ __launch_bounds__(256) void reduce_err(
    const float* __restrict__ bce, float* __restrict__ errOut) {
  float s = 0.0f;
  for (int i = threadIdx.x; i < B_DIM; i += 256) s += bce[i];
#pragma unroll
  for (int off = 32; off > 0; off >>= 1) s += __shfl_down(s, off, 64);
  __shared__ float red[4];
  if ((threadIdx.x & 63) == 0) red[threadIdx.x >> 6] = s;
  __syncthreads();
  if (threadIdx.x == 0) errOut[0] = red[0] + red[1] + red[2] + red[3];
}

extern "C" void kernel_launch(void* const* d_in, const int* in_sizes, int n_in,
                              void* d_out, int out_size, void* d_ws, size_t ws_size,
                              hipStream_t stream) {
  (void)in_sizes; (void)n_in; (void)out_size;
  const float* state  = (const float*)d_in[0];
  const float* inputX = (const float*)d_in[1];
  const float* inputY = (const float*)d_in[2];
  const float* truth  = (const float*)d_in[3];
  const float* W_t    = (const float*)d_in[4];
  const float* b_t    = (const float*)d_in[5];
  const float* W_x    = (const float*)d_in[6];
  const float* b_x    = (const float*)d_in[7];
  const float* W_y    = (const float*)d_in[8];
  const float* b_y    = (const float*)d_in[9];

  const size_t XC_B = (size_t)B_DIM * K_DIM * 2;   // 41.9 MB
  const size_t WC_B = (size_t)H_DIM * K_DIM * 2;   // 10.5 MB
  const size_t PART = (size_t)B_DIM * H_DIM * 2;   // 8.4 MB per split (bf16)

  int S = 1;
  if (ws_size >= XC_B + WC_B + 4 * PART + 16384) S = 4;
  else if (ws_size >= XC_B + WC_B + 2 * PART + 16384) S = 2;

  short* Xc = (short*)d_ws;
  short* Wc = (short*)((char*)d_ws + XC_B);
  short* P  = (short*)((char*)d_ws + XC_B + WC_B);
  float* bce = (float*)((char*)d_ws + XC_B + WC_B + (size_t)S * PART);

  float* predOut = (float*)d_out;             // [0 .. 4095]
  float* errOut  = predOut + B_DIM;           // [4096]
  float* hidden  = predOut + B_DIM + 1;       // [4097 ..]

  cast_v4<<<(B_DIM / 128 + H_DIM / 128) * (NKT / 4), 256, 0, stream>>>(
      state, inputX, W_t, W_x, Xc, Wc);

  gemm_8ph<<<64 * S, 512, 0, stream>>>(Xc, Wc, P, NKT / S);

  fuse_row<<<B_DIM, 256, 0, stream>>>(P, b_t, b_x, inputY, truth, W_y, b_y,
                                      predOut, hidden, bce, S);
  reduce_err<<<1, 256, 0, stream>>>(bce, errOut);
}

// Round 17
// 92.830 us; speedup vs baseline: 1.5058x; 1.0362x over previous
//
#include <hip/hip_runtime.h>
#include <stdint.h>
#include <math.h>

#define B_DIM 4096
#define H_DIM 1024
#define NI_DIM 4096
#define NQ_DIM 2048
#define K_DIM 5120   // H + NI
#define NKT 160      // K_DIM / 32

typedef __attribute__((ext_vector_type(8))) short short8;
typedef __attribute__((ext_vector_type(4))) float f32x4;

__device__ __forceinline__ unsigned short f2bf(float f) {
  unsigned u = __float_as_uint(f);
  u += 0x7FFFu + ((u >> 16) & 1u);  // round-to-nearest-even
  return (unsigned short)(u >> 16);
}
__device__ __forceinline__ float bf2f(unsigned short s) {
  return __uint_as_float(((unsigned)s) << 16);
}
__device__ __forceinline__ unsigned pkbf(float a, float b) {
  unsigned r;
  asm("v_cvt_pk_bf16_f32 %0, %1, %2" : "=v"(r) : "v"(a), "v"(b));
  return r;
}

__device__ __forceinline__ void gload_lds16(const void* g, void* l) {
  __builtin_amdgcn_global_load_lds(
      (__attribute__((address_space(1))) void*)(uintptr_t)g,
      (__attribute__((address_space(3))) void*)l, 16, 0, 0);
}

// fp32 -> bf16 cast into staged-tile layout (proven, ~47us; RFO-bound --
// NT stores make IT faster but poison the gemm's L2 locality: net loss).
// Block = (rowTile, ktb4): 128 rows x 128 fp32 cols = 4 consecutive kt-tiles.
__global__ __launch_bounds__(256) void cast_v4(
    const float* __restrict__ X0, const float* __restrict__ X1,
    const float* __restrict__ W0, const float* __restrict__ W1,
    short* __restrict__ Xc, short* __restrict__ Wc) {
  __shared__ __align__(16) short lds[16384];  // 2048 chunks x 8 shorts
  int bt = blockIdx.x;
  const float *s0, *s1;
  short* dst;
  if (bt < (B_DIM / 128) * (NKT / 4)) { s0 = X0; s1 = X1; dst = Xc; }
  else { bt -= (B_DIM / 128) * (NKT / 4); s0 = W0; s1 = W1; dst = Wc; }
  const int rowTile = bt / (NKT / 4);
  const int K0 = (bt % (NKT / 4)) * 4;       // first kt of this block
  const float* src;
  int cols, colBase;
  if (K0 < 32) { src = s0; cols = 1024; colBase = K0 * 32; }
  else         { src = s1; cols = 4096; colBase = (K0 - 32) * 32; }
  const int tid = threadIdx.x;
  const int kc = tid & 31;      // float4 col chunk within 128 cols
  const int r0 = tid >> 5;      // starting row (8 rows per pass)
#pragma unroll
  for (int i = 0; i < 16; ++i) {
    int r = r0 + i * 8;
    float4 v = *(const float4*)(src +
        (long long)(rowTile * 128 + r) * cols + colBase + kc * 4);
    uint2 o;
    o.x = pkbf(v.x, v.y);
    o.y = pkbf(v.z, v.w);
    int l = (kc >> 1) * 128 + r;          // logical chunk (s16*128 + r)
    int p = l ^ ((l >> 7) & 7);           // physical (bank-spread)
    *(uint2*)(&lds[p * 8 + (kc & 1) * 4]) = o;
  }
  __syncthreads();
  short* dbase = dst + ((long long)rowTile * NKT + K0) * 4096;
#pragma unroll
  for (int i = 0; i < 8; ++i) {
    int c = tid + i * 256;
    int p = c ^ ((c >> 7) & 7);
    *(short8*)(dbase + c * 8) = *(const short8*)(&lds[p * 8]);
  }
}

// LDS byte-swizzle for the epilogue transpose buffer [col][row] bf16.
__device__ __forceinline__ int ep_swz(int col, int rw) {
  int byte = col * 512 + rw * 2;           // [col 0..255][row 0..255]
  byte ^= ((col ^ (col >> 3)) & 7) << 4;   // spread banks, keeps 8B align
  return byte;
}

// 256x256-tile split-K GEMM, BK=64, 512 threads, 8 waves (2M x 4N, wave
// tile 128x64, acc[8][4]). Plain compiler-scheduled 2-phase loop --
// every hand-scheduled variant (R4/R12/R16) measured slower. Part of the
// best end-to-end configuration (R11: 92.2us total).
__global__ __launch_bounds__(512, 2) void gemm_256(
    const short* __restrict__ Xc, const short* __restrict__ Wc,
    short* __restrict__ P, int ntile) {   // ntile = 80/S K-tiles of 64
  __shared__ __align__(16) short SH[65536];  // [slot][A 4x4096 | B 4x4096]
  const int tid = threadIdx.x;
  const int lane = tid & 63;
  const int wid = tid >> 6;            // 0..7
  const int wr = wid >> 2, wc = wid & 3;
  const int fr = lane & 15, fq = lane >> 4;

  const int nwg = gridDim.x;           // 64*S, divisible by 8
  const int orig = blockIdx.x;
  const int cpx = nwg >> 3;
  const int swz = (orig & 7) * cpx + (orig >> 3);
  const int bz = swz >> 6;             // split index
  const int bm = (swz >> 2) & 15;      // 256-row tile
  const int bn = swz & 3;              // 256-col tile
  const int kt0 = bz * (2 * ntile);    // first 32-k subtile of this split

  // global subtile base pointers (each subtile = 4096 shorts, contiguous)
  const short* gA0 = Xc + ((long long)((bm * 2 + 0) * NKT + kt0) << 12);
  const short* gA2 = Xc + ((long long)((bm * 2 + 1) * NKT + kt0) << 12);
  const short* gB0 = Wc + ((long long)((bn * 2 + 0) * NKT + kt0) << 12);
  const short* gB2 = Wc + ((long long)((bn * 2 + 1) * NKT + kt0) << 12);

  f32x4 acc[8][4] = {};

  const int t8 = tid * 8;

  // prologue: stage tile 0 into slot 0
  {
    gload_lds16(gA0 + t8, &SH[t8]);
    gload_lds16(gA0 + 4096 + t8, &SH[4096 + t8]);
    gload_lds16(gA2 + t8, &SH[8192 + t8]);
    gload_lds16(gA2 + 4096 + t8, &SH[12288 + t8]);
    gload_lds16(gB0 + t8, &SH[16384 + t8]);
    gload_lds16(gB0 + 4096 + t8, &SH[20480 + t8]);
    gload_lds16(gB2 + t8, &SH[24576 + t8]);
    gload_lds16(gB2 + 4096 + t8, &SH[28672 + t8]);
  }
  __syncthreads();

  int cur = 0;
  for (int t = 0; t < ntile; ++t) {
    if (t + 1 < ntile) {  // stage tile t+1 into the other slot (issue early)
      long long off = (long long)(t + 1) * 8192 + t8;
      short* L = &SH[(cur ^ 1) * 32768];
      gload_lds16(gA0 + off, L + t8);
      gload_lds16(gA0 + 4096 + off, L + 4096 + t8);
      gload_lds16(gA2 + off, L + 8192 + t8);
      gload_lds16(gA2 + 4096 + off, L + 12288 + t8);
      gload_lds16(gB0 + off, L + 16384 + t8);
      gload_lds16(gB0 + 4096 + off, L + 20480 + t8);
      gload_lds16(gB2 + off, L + 24576 + t8);
      gload_lds16(gB2 + 4096 + off, L + 28672 + t8);
    }
    const short* aS = &SH[cur * 32768] + wr * 8192;           // h = wr
    const short* bS = &SH[cur * 32768 + 16384] + (wc >> 1) * 8192;
    const int brow = (wc & 1) * 64;
#pragma unroll
    for (int ks = 0; ks < 2; ++ks) {
      short8 av[8], bv[4];
#pragma unroll
      for (int mi = 0; mi < 8; ++mi)
        av[mi] = *(const short8*)(aS + ks * 4096 +
                                  (fq * 128 + mi * 16 + fr) * 8);
#pragma unroll
      for (int ni = 0; ni < 4; ++ni)
        bv[ni] = *(const short8*)(bS + ks * 4096 +
                                  (fq * 128 + brow + ni * 16 + fr) * 8);
#pragma unroll
      for (int mi = 0; mi < 8; ++mi)
#pragma unroll
        for (int ni = 0; ni < 4; ++ni)
          acc[mi][ni] = __builtin_amdgcn_mfma_f32_16x16x32_bf16(
              av[mi], bv[ni], acc[mi][ni], 0, 0, 0);
    }
    __syncthreads();
    cur ^= 1;
  }

  // ---- epilogue: bf16 transpose through the full 128KB LDS ----
  // phase 1: lane writes 4 consecutive rows per fragment into [col][row].
#pragma unroll
  for (int ni = 0; ni < 4; ++ni) {
    int col = wc * 64 + ni * 16 + fr;
#pragma unroll
    for (int mi = 0; mi < 8; ++mi) {
      int rw = wr * 128 + mi * 16 + fq * 4;
      uint2 pk;
      pk.x = (unsigned)f2bf(acc[mi][ni][0]) |
             ((unsigned)f2bf(acc[mi][ni][1]) << 16);
      pk.y = (unsigned)f2bf(acc[mi][ni][2]) |
             ((unsigned)f2bf(acc[mi][ni][3]) << 16);
      *(uint2*)((char*)SH + ep_swz(col, rw)) = pk;
    }
  }
  __syncthreads();
  // phase 2: read row-major chunks (8 cols) back, short8 store to P.
  short* Pp = P + (long long)bz * B_DIM * H_DIM;
#pragma unroll
  for (int h = 0; h < 16; ++h) {
    int chunk = tid + h * 512;        // 8192 chunks = 256 rows x 32 colblocks
    int rr = chunk >> 5;
    int j = chunk & 31;
    short8 o;
#pragma unroll
    for (int k = 0; k < 8; ++k) {
      o[k] = *(const short*)((char*)SH + ep_swz(j * 8 + k, rr));
    }
    *(short8*)(Pp + (long long)(bm * 256 + rr) * H_DIM + bn * 256 + j * 8) = o;
  }
}

// Fused: per-row split-K reduce + bias + tanh + hidden write + one-hot
// select + Wy dot + sigmoid + per-row BCE into bce[b]. (R14: never
// atomicAdd 4096 blocks into one address -- 66us serialization.)
__global__ __launch_bounds__(256) void fuse_row(
    const short* __restrict__ P, const float* __restrict__ bt,
    const float* __restrict__ bx, const float* __restrict__ Y,
    const float* __restrict__ truth, const float* __restrict__ Wy,
    const float* __restrict__ by, float* __restrict__ predOut,
    float* __restrict__ hidden, float* __restrict__ bce, int S) {
  const int b = blockIdx.x;
  const int tid = threadIdx.x;
  __shared__ int s_cnt;
  __shared__ int s_idx[8];
  __shared__ float s_val[8];
  __shared__ float s_red[4];
  if (tid == 0) s_cnt = 0;

  const int c = tid * 4;
  float s0 = 0.f, s1 = 0.f, s2 = 0.f, s3 = 0.f;
  for (int z = 0; z < S; ++z) {
    const short* Pr = P + ((long long)z * B_DIM + b) * H_DIM + c;
    uint2 u = *(const uint2*)Pr;
    s0 += bf2f((unsigned short)(u.x & 0xffff));
    s1 += bf2f((unsigned short)(u.x >> 16));
    s2 += bf2f((unsigned short)(u.y & 0xffff));
    s3 += bf2f((unsigned short)(u.y >> 16));
  }
  float4 bt4 = *(const float4*)(bt + c);
  float4 bx4 = *(const float4*)(bx + c);
  float h0 = tanhf(s0 + bt4.x + bx4.x);
  float h1 = tanhf(s1 + bt4.y + bx4.y);
  float h2 = tanhf(s2 + bt4.z + bx4.z);
  float h3 = tanhf(s3 + bt4.w + bx4.w);
  float* Hr = hidden + (long long)b * H_DIM + c;  // base unaligned -> scalar
  Hr[0] = h0; Hr[1] = h1; Hr[2] = h2; Hr[3] = h3;

  __syncthreads();  // covers s_cnt init
  const float4* Yr = (const float4*)(Y + (long long)b * NQ_DIM);
#pragma unroll
  for (int hh = 0; hh < NQ_DIM / 4 / 256; ++hh) {
    int j = tid + hh * 256;
    float4 v = Yr[j];
    if (v.x != 0.0f) { int p = atomicAdd(&s_cnt, 1); if (p < 8) { s_idx[p] = 4 * j;     s_val[p] = v.x; } }
    if (v.y != 0.0f) { int p = atomicAdd(&s_cnt, 1); if (p < 8) { s_idx[p] = 4 * j + 1; s_val[p] = v.y; } }
    if (v.z != 0.0f) { int p = atomicAdd(&s_cnt, 1); if (p < 8) { s_idx[p] = 4 * j + 2; s_val[p] = v.z; } }
    if (v.w != 0.0f) { int p = atomicAdd(&s_cnt, 1); if (p < 8) { s_idx[p] = 4 * j + 3; s_val[p] = v.w; } }
  }
  __syncthreads();
  int cnt = s_cnt < 8 ? s_cnt : 8;
  float predv = 0.0f;
  for (int it = 0; it < cnt; ++it) {
    int q = s_idx[it];
    float4 w = *(const float4*)(Wy + (long long)q * H_DIM + c);
    float part = h0 * w.x + h1 * w.y + h2 * w.z + h3 * w.w;
#pragma unroll
    for (int off = 32; off > 0; off >>= 1) part += __shfl_down(part, off, 64);
    if ((tid & 63) == 0) s_red[tid >> 6] = part;
    __syncthreads();
    if (tid == 0) {
      float z = s_red[0] + s_red[1] + s_red[2] + s_red[3] + by[q];
      float p = 1.0f / (1.0f + expf(-z));
      predv += s_val[it] * p;
    }
    __syncthreads();
  }
  if (tid == 0) {
    predOut[b] = predv;
    float t = truth[b];
    float lp = fmaxf(logf(predv), -100.0f);
    float l1p = fmaxf(log1pf(-predv), -100.0f);
    bce[b] = -(t * lp + (1.0f - t) * l1p);
  }
}

__global__ __launch_bounds__(256) void reduce_err(
    const float* __restrict__ bce, float* __restrict__ errOut) {
  float s = 0.0f;
  for (int i = threadIdx.x; i < B_DIM; i += 256) s += bce[i];
#pragma unroll
  for (int off = 32; off > 0; off >>= 1) s += __shfl_down(s, off, 64);
  __shared__ float red[4];
  if ((threadIdx.x & 63) == 0) red[threadIdx.x >> 6] = s;
  __syncthreads();
  if (threadIdx.x == 0) errOut[0] = red[0] + red[1] + red[2] + red[3];
}

extern "C" void kernel_launch(void* const* d_in, const int* in_sizes, int n_in,
                              void* d_out, int out_size, void* d_ws, size_t ws_size,
                              hipStream_t stream) {
  (void)in_sizes; (void)n_in; (void)out_size;
  const float* state  = (const float*)d_in[0];
  const float* inputX = (const float*)d_in[1];
  const float* inputY = (const float*)d_in[2];
  const float* truth  = (const float*)d_in[3];
  const float* W_t    = (const float*)d_in[4];
  const float* b_t    = (const float*)d_in[5];
  const float* W_x    = (const float*)d_in[6];
  const float* b_x    = (const float*)d_in[7];
  const float* W_y    = (const float*)d_in[8];
  const float* b_y    = (const float*)d_in[9];

  const size_t XC_B = (size_t)B_DIM * K_DIM * 2;   // 41.9 MB
  const size_t WC_B = (size_t)H_DIM * K_DIM * 2;   // 10.5 MB
  const size_t PART = (size_t)B_DIM * H_DIM * 2;   // 8.4 MB per split (bf16)

  int S = 1;
  if (ws_size >= XC_B + WC_B + 4 * PART + 16384) S = 4;
  else if (ws_size >= XC_B + WC_B + 2 * PART + 16384) S = 2;

  short* Xc = (short*)d_ws;
  short* Wc = (short*)((char*)d_ws + XC_B);
  short* P  = (short*)((char*)d_ws + XC_B + WC_B);
  float* bce = (float*)((char*)d_ws + XC_B + WC_B + (size_t)S * PART);

  float* predOut = (float*)d_out;             // [0 .. 4095]
  float* errOut  = predOut + B_DIM;           // [4096]
  float* hidden  = predOut + B_DIM + 1;       // [4097 ..]

  cast_v4<<<(B_DIM / 128 + H_DIM / 128) * (NKT / 4), 256, 0, stream>>>(
      state, inputX, W_t, W_x, Xc, Wc);

  gemm_256<<<64 * S, 512, 0, stream>>>(Xc, Wc, P, 80 / S);

  fuse_row<<<B_DIM, 256, 0, stream>>>(P, b_t, b_x, inputY, truth, W_y, b_y,
                                      predOut, hidden, bce, S);
  reduce_err<<<1, 256, 0, stream>>>(bce, errOut);
}